// Round 10
// baseline (431.355 us; speedup 1.0000x reference)
//
#include <hip/hip_runtime.h>
#include <cstddef>

static constexpr int B_  = 256;
static constexpr int L_  = 64;
static constexpr int H_  = 1024;
static constexpr int IN_ = 512;
static constexpr int V_  = 32000;

typedef __attribute__((ext_vector_type(8))) short bf8;
typedef __attribute__((ext_vector_type(4))) short s4;
typedef __attribute__((ext_vector_type(4))) float f32x4;

__device__ __forceinline__ short f2b(float x) {
    unsigned u = __float_as_uint(x);
    u += 0x7fffu + ((u >> 16) & 1u);
    return (short)(u >> 16);
}
__device__ __forceinline__ float b2f(short s) {
    unsigned u = ((unsigned)(unsigned short)s) << 16;
    return __uint_as_float(u);
}
__device__ __forceinline__ bf8 pack8(const float4& a, const float4& b) {
    bf8 r;
    r[0]=f2b(a.x); r[1]=f2b(a.y); r[2]=f2b(a.z); r[3]=f2b(a.w);
    r[4]=f2b(b.x); r[5]=f2b(b.y); r[6]=f2b(b.z); r[7]=f2b(b.w);
    return r;
}
__device__ __forceinline__ void gload_lds16(const void* g, void* l) {
    __builtin_amdgcn_global_load_lds(
        (const __attribute__((address_space(1))) unsigned int*)g,
        (__attribute__((address_space(3))) unsigned int*)l, 16, 0, 0);
}

// ---------------- conversion kernels ----------------
__global__ __launch_bounds__(256) void conv_static(
    const float* __restrict__ h, const float* __restrict__ emb,
    short* __restrict__ h_bf, short* __restrict__ xgi, short* __restrict__ xlo)
{
    int u = blockIdx.x * 256 + threadIdx.x;          // float4 units
    if (u < 65536) {                                  // h: 256*1024/4
        float4 f = *(const float4*)(h + (size_t)u * 4);
        s4 s; s[0]=f2b(f.x); s[1]=f2b(f.y); s[2]=f2b(f.z); s[3]=f2b(f.w);
        *(s4*)(h_bf + (size_t)u * 4) = s;
    } else {                                          // emb: 256*512/4 = 32768
        int e = u - 65536;
        int m = e >> 7, c4 = (e & 127) * 4;
        float4 f = *(const float4*)(emb + (size_t)m * 512 + c4);
        s4 s; s[0]=f2b(f.x); s[1]=f2b(f.y); s[2]=f2b(f.z); s[3]=f2b(f.w);
        *(s4*)(xgi + (size_t)m * 2560 + c4) = s;
        *(s4*)(xlo + (size_t)m * 3584 + 3072 + c4) = s;
    }
}

// W_attn[:,1024:3072] -> Wb [1024][2048] bf16, chunk-swizzled: p ^ (n&7)
__global__ __launch_bounds__(256) void conv_wattn2(
    const float* __restrict__ W_attn, short* __restrict__ Wb)
{
    int o = blockIdx.x * 256 + threadIdx.x;           // 262144 chunks of 8
    int n = o >> 8, rest = o & 255;
    int t = rest >> 3, p = rest & 7;
    int c = p ^ (n & 7);
    const float* src = W_attn + (size_t)n * 3072 + 1024 + t * 64 + c * 8;
    float4 f0 = *(const float4*)src;
    float4 f1 = *(const float4*)(src + 4);
    *(bf8*)(Wb + (size_t)n * 2048 + t * 64 + p * 8) = pack8(f0, f1);
}

// enc -> enc_bf [16384][2048] bf16 in m-order, chunk-swizzled: p ^ (m&7)
__global__ __launch_bounds__(256) void conv_enc(
    const float* __restrict__ enc, short* __restrict__ enc_bf)
{
    int o = blockIdx.x * 256 + threadIdx.x;           // 4194304 chunks of 8
    int m = o >> 8, rest = o & 255;
    int t = rest >> 3, p = rest & 7;
    int c = p ^ (m & 7);
    int b = m >> 6, l = m & 63;
    const float* src = enc + ((size_t)l * B_ + b) * 2048 + t * 64 + c * 8;
    float4 f0 = *(const float4*)src;
    float4 f1 = *(const float4*)(src + 4);
    *(bf8*)(enc_bf + (size_t)m * 2048 + t * 64 + p * 8) = pack8(f0, f1);
}

// ---------------- GEMM (reg-staged LDS): small GEMMs (E1+gh, gi) ----------------
template<int MODE>
__global__ __launch_bounds__(256) void gemm3(
    const short* __restrict__ Xb, int ldx, int K,
    const float* __restrict__ W0, int ldw0,
    const float* __restrict__ W1,
    const float* __restrict__ bias,
    float* __restrict__ out0, int ldo0,
    float* __restrict__ out1)
{
    __shared__ short Xs[256 * 64];
    __shared__ short Ws[64 * 64];

    const int tid = threadIdx.x;
    const int n0 = blockIdx.x * 64;
    const int wid = tid >> 6, lane = tid & 63;
    const int ln15 = lane & 15, kq = lane >> 4;

    const float* Wsrc; int ldw;
    if (MODE == 1) {
        if (n0 < 1024) { Wsrc = W0 + (size_t)n0 * ldw0; ldw = ldw0; }
        else           { Wsrc = W1 + (size_t)(n0 - 1024) * 1024; ldw = 1024; }
    } else { Wsrc = W0 + (size_t)n0 * ldw0; ldw = ldw0; }

    int xdst[8]; const short* xsrc[8];
    #pragma unroll
    for (int c = 0; c < 8; ++c) {
        int o = c * 256 + tid;
        int row = o >> 3, cb = o & 7;
        xsrc[c] = Xb + (size_t)row * ldx + cb * 8;
        xdst[c] = row * 64 + ((cb * 8) ^ ((row & 7) << 3));
    }
    int wdst[2]; const float* wsrcp[2];
    #pragma unroll
    for (int g = 0; g < 2; ++g) {
        int o = g * 256 + tid;
        int row = o >> 3, gb = o & 7;
        wsrcp[g] = Wsrc + (size_t)row * ldw + gb * 8;
        wdst[g] = row * 64 + ((gb * 8) ^ ((row & 7) << 3));
    }
    int aoff[2][4], boff[2][4];
    #pragma unroll
    for (int ks = 0; ks < 2; ++ks) {
        #pragma unroll
        for (int i = 0; i < 4; ++i) {
            int ar = wid * 64 + i * 16 + ln15;
            aoff[ks][i] = ar * 64 + ((ks * 32 + kq * 8) ^ ((ar & 7) << 3));
            int br = i * 16 + ln15;
            boff[ks][i] = br * 64 + ((ks * 32 + kq * 8) ^ ((br & 7) << 3));
        }
    }

    f32x4 acc[4][4];
    #pragma unroll
    for (int i = 0; i < 4; ++i)
        #pragma unroll
        for (int j = 0; j < 4; ++j) acc[i][j] = {0.f, 0.f, 0.f, 0.f};

    bf8 xA[8], xB[8];
    float4 wA[4], wB[4];

    const int NT = K >> 6;

    #pragma unroll
    for (int c = 0; c < 8; ++c) xA[c] = *(const bf8*)(xsrc[c]);
    #pragma unroll
    for (int g = 0; g < 2; ++g) {
        wA[2*g]   = *(const float4*)(wsrcp[g]);
        wA[2*g+1] = *(const float4*)(wsrcp[g] + 4);
    }

    for (int t = 0; t < NT; t += 2) {
        __syncthreads();
        #pragma unroll
        for (int c = 0; c < 8; ++c) *(bf8*)&Xs[xdst[c]] = xA[c];
        #pragma unroll
        for (int g = 0; g < 2; ++g) *(bf8*)&Ws[wdst[g]] = pack8(wA[2*g], wA[2*g+1]);
        if (t + 1 < NT) {
            int k0 = (t + 1) << 6;
            #pragma unroll
            for (int c = 0; c < 8; ++c) xB[c] = *(const bf8*)(xsrc[c] + k0);
            #pragma unroll
            for (int g = 0; g < 2; ++g) {
                wB[2*g]   = *(const float4*)(wsrcp[g] + k0);
                wB[2*g+1] = *(const float4*)(wsrcp[g] + k0 + 4);
            }
        }
        __syncthreads();
        #pragma unroll
        for (int ks = 0; ks < 2; ++ks) {
            bf8 a[4], b[4];
            #pragma unroll
            for (int i = 0; i < 4; ++i) a[i] = *(const bf8*)&Xs[aoff[ks][i]];
            #pragma unroll
            for (int j = 0; j < 4; ++j) b[j] = *(const bf8*)&Ws[boff[ks][j]];
            #pragma unroll
            for (int i = 0; i < 4; ++i)
                #pragma unroll
                for (int j = 0; j < 4; ++j)
                    acc[i][j] = __builtin_amdgcn_mfma_f32_16x16x32_bf16(a[i], b[j], acc[i][j], 0, 0, 0);
        }
        if (t + 1 >= NT) break;
        __syncthreads();
        #pragma unroll
        for (int c = 0; c < 8; ++c) *(bf8*)&Xs[xdst[c]] = xB[c];
        #pragma unroll
        for (int g = 0; g < 2; ++g) *(bf8*)&Ws[wdst[g]] = pack8(wB[2*g], wB[2*g+1]);
        if (t + 2 < NT) {
            int k0 = (t + 2) << 6;
            #pragma unroll
            for (int c = 0; c < 8; ++c) xA[c] = *(const bf8*)(xsrc[c] + k0);
            #pragma unroll
            for (int g = 0; g < 2; ++g) {
                wA[2*g]   = *(const float4*)(wsrcp[g] + k0);
                wA[2*g+1] = *(const float4*)(wsrcp[g] + k0 + 4);
            }
        }
        __syncthreads();
        #pragma unroll
        for (int ks = 0; ks < 2; ++ks) {
            bf8 a[4], b[4];
            #pragma unroll
            for (int i = 0; i < 4; ++i) a[i] = *(const bf8*)&Xs[aoff[ks][i]];
            #pragma unroll
            for (int j = 0; j < 4; ++j) b[j] = *(const bf8*)&Ws[boff[ks][j]];
            #pragma unroll
            for (int i = 0; i < 4; ++i)
                #pragma unroll
                for (int j = 0; j < 4; ++j)
                    acc[i][j] = __builtin_amdgcn_mfma_f32_16x16x32_bf16(a[i], b[j], acc[i][j], 0, 0, 0);
        }
    }

    #pragma unroll
    for (int i = 0; i < 4; ++i) {
        #pragma unroll
        for (int j = 0; j < 4; ++j) {
            int col = n0 + j * 16 + ln15;
            #pragma unroll
            for (int r = 0; r < 4; ++r) {
                int row = wid * 64 + i * 16 + kq * 4 + r;
                float v = acc[i][j][r];
                if (MODE == 1) {
                    if (n0 < 1024) out0[(size_t)row * ldo0 + col] = v;
                    else           out1[(size_t)row * 3072 + (col - 1024)] = v + bias[col - 1024];
                } else {
                    out0[(size_t)row * ldo0 + col] = v + (bias ? bias[col] : 0.f);
                }
            }
        }
    }
}

// ---------------- logits5: W f32 via global_load_lds, A direct from L2 ----------------
// out[256,32000] = Xb[256,3584](bf16) @ W[32000,3584](f32)^T + bias.
// BM=256(=M), BN=64, BK=64. 256 thr = 4 waves; wave w owns rows 64w..64w+63;
// all waves share the 64-col W tile. W streamed HBM->LDS via global_load_lds
// (single-barrier double-buffer, m97 pattern); bf16 conversion at fragment read.
// W LDS row = 64 f32 = 256B = 16 chunks of 16B; pre-swizzle p = c ^ ((row&7)<<1)
// (preserves 32B pairs); reads use the same XOR at 32B-unit granularity.
__global__ __launch_bounds__(256) void logits5(
    const short* __restrict__ Xb,   // [256][3584] bf16
    const float* __restrict__ W,    // [32000][3584] f32
    const float* __restrict__ bias,
    float* __restrict__ out)
{
    __shared__ float Wf[2][64 * 64];    // 16 KB per buf

    const int tid = threadIdx.x;
    const int n0 = blockIdx.x * 64;
    const int wid = tid >> 6, lane = tid & 63;
    const int ln15 = lane & 15, kq = lane >> 4;
    const int m0 = wid * 64;

    // W staging: 1024 chunks of 16B per tile, 4 per thread; pre-swizzled source
    const char* wg[4]; int wl[4];
    #pragma unroll
    for (int c = 0; c < 4; ++c) {
        int chunk = c * 256 + tid;
        int row = chunk >> 4, p = chunk & 15;
        int lc = p ^ ((row & 7) << 1);                 // logical chunk
        wg[c] = (const char*)W + (size_t)(n0 + row) * 14336 + lc * 16;
        wl[c] = chunk * 16;
    }
    // B-fragment byte offsets: ks in {0,1}, j in 0..3; r = j*16+ln15,
    // 32B unit u = ks*4+kq -> phys u^(r&7); two b128 at +0,+16
    int boff[2][4];
    #pragma unroll
    for (int ks = 0; ks < 2; ++ks) {
        #pragma unroll
        for (int j = 0; j < 4; ++j) {
            int r = j * 16 + ln15;
            int u = (ks * 4 + kq) ^ (r & 7);
            boff[ks][j] = r * 256 + u * 32;
        }
    }
    // A sources (L2-resident bf16)
    const short* asrc[4];
    #pragma unroll
    for (int i = 0; i < 4; ++i)
        asrc[i] = Xb + (size_t)(m0 + i * 16 + ln15) * 3584 + kq * 8;

    f32x4 acc[4][4];
    #pragma unroll
    for (int i = 0; i < 4; ++i)
        #pragma unroll
        for (int j = 0; j < 4; ++j) acc[i][j] = {0.f, 0.f, 0.f, 0.f};

    // prologue: stage tile 0
    #pragma unroll
    for (int c = 0; c < 4; ++c) gload_lds16(wg[c], (char*)&Wf[0][0] + wl[c]);
    __syncthreads();

    const int NT = 3584 / 64;   // 56
    for (int t = 0; t < NT; ++t) {
        int cur = t & 1;
        if (t + 1 < NT) {
            size_t k0 = (size_t)(t + 1) * 256;   // 64 f32 per row-tile step
            #pragma unroll
            for (int c = 0; c < 4; ++c) gload_lds16(wg[c] + k0, (char*)&Wf[cur ^ 1][0] + wl[c]);
        }
        const char* wb = (const char*)&Wf[cur][0];
        #pragma unroll
        for (int ks = 0; ks < 2; ++ks) {
            int ka = t * 64 + ks * 32;
            bf8 a[4], b[4];
            #pragma unroll
            for (int i = 0; i < 4; ++i) a[i] = *(const bf8*)(asrc[i] + ka);
            #pragma unroll
            for (int j = 0; j < 4; ++j) {
                float4 f0 = *(const float4*)(wb + boff[ks][j]);
                float4 f1 = *(const float4*)(wb + boff[ks][j] + 16);
                b[j] = pack8(f0, f1);
            }
            #pragma unroll
            for (int i = 0; i < 4; ++i)
                #pragma unroll
                for (int j = 0; j < 4; ++j)
                    acc[i][j] = __builtin_amdgcn_mfma_f32_16x16x32_bf16(a[i], b[j], acc[i][j], 0, 0, 0);
        }
        __syncthreads();
    }

    // epilogue: col=lane&15 (n), row=(lane>>4)*4+r (m)
    #pragma unroll
    for (int j = 0; j < 4; ++j) {
        int col = n0 + j * 16 + ln15;
        float bv = bias[col];
        #pragma unroll
        for (int i = 0; i < 4; ++i) {
            #pragma unroll
            for (int r = 0; r < 4; ++r) {
                int row = m0 + i * 16 + kq * 4 + r;
                out[(size_t)row * 32000 + col] = acc[i][j][r] + bv;
            }
        }
    }
}

// ---------------- energy4: m97-structure, both operands bf16 via global_load_lds ----------------
__global__ __launch_bounds__(256) void energy4(
    const short* __restrict__ enc_bf,   // [16384][2048] bf16, chunk-swizzled
    const short* __restrict__ Wb,       // [1024][2048] bf16, chunk-swizzled
    const float* __restrict__ E1,       // [256][1024]
    const float* __restrict__ b_attn,
    const float* __restrict__ v_attn,
    float* __restrict__ partials)       // [16384][16]
{
    __shared__ short As[2][128 * 64];   // 16 KB per buf
    __shared__ short Bs[2][128 * 64];   // 16 KB per buf

    const int tid = threadIdx.x;
    const int p = blockIdx.x;                     // 0..1023
    const int wgid = (p & 7) * 128 + (p >> 3);    // XCD chunk
    const int mb = wgid >> 3, nb = wgid & 7;
    const int m0 = mb * 128, n0 = nb * 128;
    const int wid = tid >> 6, lane = tid & 63;
    const int wrow = wid >> 1, wcol = wid & 1;
    const int ln15 = lane & 15, kq = lane >> 4;

    const char* ag[4]; const char* bg[4]; int ldst[4];
    #pragma unroll
    for (int c = 0; c < 4; ++c) {
        int o = c * 4096 + tid * 16;
        int row = o >> 7, cb = o & 127;
        ag[c] = (const char*)enc_bf + (size_t)(m0 + row) * 4096 + cb;
        bg[c] = (const char*)Wb + (size_t)(n0 + row) * 4096 + cb;
        ldst[c] = o;
    }
    int aoff[2][4], boff[2][4];
    #pragma unroll
    for (int ks = 0; ks < 2; ++ks) {
        #pragma unroll
        for (int i = 0; i < 4; ++i) {
            int ar = wrow * 64 + i * 16 + ln15;
            aoff[ks][i] = ar * 128 + (((ks * 4 + kq) ^ (ar & 7)) << 4);
            int br = wcol * 64 + i * 16 + ln15;
            boff[ks][i] = br * 128 + (((ks * 4 + kq) ^ (br & 7)) << 4);
        }
    }

    f32x4 acc[4][4];
    #pragma unroll
    for (int i = 0; i < 4; ++i)
        #pragma unroll
        for (int j = 0; j < 4; ++j) acc[i][j] = {0.f, 0.f, 0.f, 0.f};

    #pragma unroll
    for (int c = 0; c < 4; ++c) {
        gload_lds16(ag[c], (char*)&As[0][0] + ldst[c]);
        gload_lds16(bg[c], (char*)&Bs[0][0] + ldst[c]);
    }
    __syncthreads();

    const int NT = 2048 / 64;   // 32
    for (int t = 0; t < NT; ++t) {
        int cur = t & 1;
        if (t + 1 < NT) {
            size_t k0 = (size_t)(t + 1) * 128;
            #pragma unroll
            for (int c = 0; c < 4; ++c) {
                gload_lds16(ag[c] + k0, (char*)&As[cur ^ 1][0] + ldst[c]);
                gload_lds16(bg[c] + k0, (char*)&Bs[cur ^ 1][0] + ldst[c]);
            }
        }
        const char* ab = (const char*)&As[cur][0];
        const char* bb = (const char*)&Bs[cur][0];
        #pragma unroll
        for (int ks = 0; ks < 2; ++ks) {
            bf8 a[4], b[4];
            #pragma unroll
            for (int i = 0; i < 4; ++i) a[i] = *(const bf8*)(ab + aoff[ks][i]);
            #pragma unroll
            for (int j = 0; j < 4; ++j) b[j] = *(const bf8*)(bb + boff[ks][j]);
            #pragma unroll
            for (int i = 0; i < 4; ++i)
                #pragma unroll
                for (int j = 0; j < 4; ++j)
                    acc[i][j] = __builtin_amdgcn_mfma_f32_16x16x32_bf16(a[i], b[j], acc[i][j], 0, 0, 0);
        }
        __syncthreads();
    }

    float rs[4][4];
    #pragma unroll
    for (int i = 0; i < 4; ++i)
        #pragma unroll
        for (int r = 0; r < 4; ++r) rs[i][r] = 0.f;

    #pragma unroll
    for (int i = 0; i < 4; ++i) {
        #pragma unroll
        for (int j = 0; j < 4; ++j) {
            int col = n0 + wcol * 64 + j * 16 + ln15;
            float bv = b_attn[col], vv = v_attn[col];
            #pragma unroll
            for (int r = 0; r < 4; ++r) {
                int m = m0 + wrow * 64 + i * 16 + kq * 4 + r;
                float e = tanhf(acc[i][j][r] + E1[(size_t)(m >> 6) * 1024 + col] + bv);
                rs[i][r] += e * vv;
            }
        }
    }
    #pragma unroll
    for (int i = 0; i < 4; ++i)
        #pragma unroll
        for (int r = 0; r < 4; ++r) {
            float s = rs[i][r];
            #pragma unroll
            for (int off = 1; off < 16; off <<= 1) s += __shfl_xor(s, off);
            rs[i][r] = s;
        }
    if (ln15 == 0) {
        #pragma unroll
        for (int i = 0; i < 4; ++i)
            #pragma unroll
            for (int r = 0; r < 4; ++r) {
                int m = m0 + wrow * 64 + i * 16 + kq * 4 + r;
                partials[(size_t)m * 16 + nb * 2 + wcol] = rs[i][r];
            }
    }
}

// masked softmax over L=64
__global__ __launch_bounds__(64) void softmax_k(const float* __restrict__ partials,
                                                const int* __restrict__ mask,
                                                float* __restrict__ attnw)
{
    int b = blockIdx.x;
    int l = threadIdx.x;
    float s = 0.f;
    #pragma unroll
    for (int nb = 0; nb < 16; ++nb) s += partials[(size_t)(b * 64 + l) * 16 + nb];
    if (mask[b * 64 + l] != 0) s = -1e10f;
    float m = s;
    #pragma unroll
    for (int off = 32; off; off >>= 1) m = fmaxf(m, __shfl_xor(m, off));
    float e = expf(s - m);
    float sum = e;
    #pragma unroll
    for (int off = 32; off; off >>= 1) sum += __shfl_xor(sum, off);
    attnw[b * 64 + l] = e / sum;
}

// weighted from enc_bf (chunk-unswizzled) -> bf16 into xgi[:,512:2560], xlo[:,1024:3072]
__global__ __launch_bounds__(256) void weighted3(const float* __restrict__ attnw,
                                                 const short* __restrict__ enc_bf,
                                                 short* __restrict__ xgi,
                                                 short* __restrict__ xlo)
{
    int b = blockIdx.x;
    int c = threadIdx.x;              // chunk of 8 logical cols
    int t = c >> 3, lc = c & 7;
    float acc[8] = {};
    const short* base = enc_bf + ((size_t)b * 64) * 2048 + t * 64;
    for (int l = 0; l < 64; ++l) {
        float w = attnw[b * 64 + l];
        bf8 v = *(const bf8*)(base + (size_t)l * 2048 + ((lc ^ (l & 7)) * 8));
        #pragma unroll
        for (int e = 0; e < 8; ++e) acc[e] += w * b2f(v[e]);
    }
    bf8 s;
    #pragma unroll
    for (int e = 0; e < 8; ++e) s[e] = f2b(acc[e]);
    *(bf8*)(xgi + (size_t)b * 2560 + 512 + c * 8) = s;
    *(bf8*)(xlo + (size_t)b * 3584 + 1024 + c * 8) = s;
}

// GRU gates; writes hnew (f32 output) and xlo_bf[:,0:1024]
__global__ __launch_bounds__(256) void gru2(const float* __restrict__ gi,
                                            const float* __restrict__ gh,
                                            const float* __restrict__ h,
                                            float* __restrict__ hnew,
                                            short* __restrict__ xlo)
{
    int idx = blockIdx.x * 256 + threadIdx.x;
    int b = idx >> 10, j = idx & 1023;
    const float* gib = gi + (size_t)b * 3072;
    const float* ghb = gh + (size_t)b * 3072;
    float r = 1.f / (1.f + expf(-(gib[j] + ghb[j])));
    float z = 1.f / (1.f + expf(-(gib[1024 + j] + ghb[1024 + j])));
    float n = tanhf(gib[2048 + j] + r * ghb[2048 + j]);
    float hv = (1.f - z) * n + z * h[idx];
    hnew[idx] = hv;
    xlo[(size_t)b * 3584 + j] = f2b(hv);
}

extern "C" void kernel_launch(void* const* d_in, const int* in_sizes, int n_in,
                              void* d_out, int out_size, void* d_ws, size_t ws_size,
                              hipStream_t stream) {
    const float* input_emb = (const float*)d_in[0];
    const float* hidden    = (const float*)d_in[1];
    const float* enc       = (const float*)d_in[2];
    const int*   mask      = (const int*)d_in[3];
    const float* W_attn = (const float*)d_in[4];
    const float* b_attn = (const float*)d_in[5];
    const float* v_attn = (const float*)d_in[6];
    const float* W_ih   = (const float*)d_in[7];
    const float* W_hh   = (const float*)d_in[8];
    const float* b_ih   = (const float*)d_in[9];
    const float* b_hh   = (const float*)d_in[10];
    const float* W_out  = (const float*)d_in[11];
    const float* b_out  = (const float*)d_in[12];

    float* logits = (float*)d_out;
    float* hnew   = logits + (size_t)B_ * V_;
    float* attnw  = hnew + (size_t)B_ * H_;

    float* ws       = (float*)d_ws;
    float* partials = ws;                                  // 262144 f
    float* E1       = partials + 262144;                   // 262144 f
    float* gi       = E1 + 262144;                         // 786432 f
    float* gh       = gi + 786432;                         // 786432 f
    short* h_bf     = (short*)(gh + 786432);               // 262144 sh
    short* xgi_bf   = h_bf + 262144;                       // 655360 sh
    short* xlo_bf   = xgi_bf + 655360;                     // 917504 sh
    short* Wattn2   = xlo_bf + 917504;                     // 2097152 sh
    short* enc_bf   = Wattn2 + 2097152;                    // 33554432 sh (64 MB)

    conv_static<<<384, 256, 0, stream>>>(hidden, input_emb, h_bf, xgi_bf, xlo_bf);
    conv_wattn2<<<1024, 256, 0, stream>>>(W_attn, Wattn2);
    conv_enc<<<16384, 256, 0, stream>>>(enc, enc_bf);

    // E1 (n<1024, no bias) + gh (n>=1024, +b_hh), X = h_bf
    gemm3<1><<<64, 256, 0, stream>>>(h_bf, 1024, 1024,
                                     W_attn, 3072, W_hh, b_hh, E1, 1024, gh);
    // energy (1024 blocks, XCD-chunked internally)
    energy4<<<1024, 256, 0, stream>>>(enc_bf, Wattn2, E1, b_attn, v_attn, partials);
    softmax_k<<<B_, 64, 0, stream>>>(partials, mask, attnw);
    weighted3<<<B_, 256, 0, stream>>>(attnw, enc_bf, xgi_bf, xlo_bf);
    // gi = xgi_bf * W_ih^T + b_ih
    gemm3<0><<<48, 256, 0, stream>>>(xgi_bf, 2560, 2560,
                                     W_ih, 2560, nullptr, b_ih, gi, 3072, nullptr);
    gru2<<<1024, 256, 0, stream>>>(gi, gh, hidden, hnew, xlo_bf);
    // logits: W via global_load_lds, A direct from L2
    logits5<<<500, 256, 0, stream>>>(xlo_bf, W_out, b_out, logits);
}

// Round 11
// 395.050 us; speedup vs baseline: 1.0919x; 1.0919x over previous
//
#include <hip/hip_runtime.h>
#include <cstddef>

static constexpr int B_  = 256;
static constexpr int L_  = 64;
static constexpr int H_  = 1024;
static constexpr int IN_ = 512;
static constexpr int V_  = 32000;

typedef __attribute__((ext_vector_type(8))) short bf8;
typedef __attribute__((ext_vector_type(4))) short s4;
typedef __attribute__((ext_vector_type(4))) float f32x4;

__device__ __forceinline__ short f2b(float x) {
    unsigned u = __float_as_uint(x);
    u += 0x7fffu + ((u >> 16) & 1u);
    return (short)(u >> 16);
}
__device__ __forceinline__ bf8 pack8(const float4& a, const float4& b) {
    bf8 r;
    r[0]=f2b(a.x); r[1]=f2b(a.y); r[2]=f2b(a.z); r[3]=f2b(a.w);
    r[4]=f2b(b.x); r[5]=f2b(b.y); r[6]=f2b(b.z); r[7]=f2b(b.w);
    return r;
}

// ---------------- conversion kernels ----------------
__global__ __launch_bounds__(256) void conv_static(
    const float* __restrict__ h, const float* __restrict__ emb,
    short* __restrict__ h_bf, short* __restrict__ xgi, short* __restrict__ xlo)
{
    int u = blockIdx.x * 256 + threadIdx.x;          // float4 units
    if (u < 65536) {                                  // h: 256*1024/4
        float4 f = *(const float4*)(h + (size_t)u * 4);
        s4 s; s[0]=f2b(f.x); s[1]=f2b(f.y); s[2]=f2b(f.z); s[3]=f2b(f.w);
        *(s4*)(h_bf + (size_t)u * 4) = s;
    } else {                                          // emb: 256*512/4 = 32768
        int e = u - 65536;
        int m = e >> 7, c4 = (e & 127) * 4;
        float4 f = *(const float4*)(emb + (size_t)m * 512 + c4);
        s4 s; s[0]=f2b(f.x); s[1]=f2b(f.y); s[2]=f2b(f.z); s[3]=f2b(f.w);
        *(s4*)(xgi + (size_t)m * 2560 + c4) = s;
        *(s4*)(xlo + (size_t)m * 3584 + 3072 + c4) = s;
    }
}

__global__ __launch_bounds__(256) void conv_wattn2(
    const float* __restrict__ W_attn, short* __restrict__ Wb)
{
    int o = blockIdx.x * 256 + threadIdx.x;           // float4 units, 524288
    int r = o >> 9, c4 = (o & 511) * 4;
    float4 f = *(const float4*)(W_attn + (size_t)r * 3072 + 1024 + c4);
    s4 s; s[0]=f2b(f.x); s[1]=f2b(f.y); s[2]=f2b(f.z); s[3]=f2b(f.w);
    *(s4*)(Wb + (size_t)r * 2048 + c4) = s;
}

// ---------------- GEMM (reg-staged LDS): small GEMMs (E1+gh, gi) ----------------
template<int MODE>
__global__ __launch_bounds__(256) void gemm3(
    const short* __restrict__ Xb, int ldx, int K,
    const float* __restrict__ W0, int ldw0,
    const float* __restrict__ W1,
    const float* __restrict__ bias,
    float* __restrict__ out0, int ldo0,
    float* __restrict__ out1)
{
    __shared__ short Xs[256 * 64];
    __shared__ short Ws[64 * 64];

    const int tid = threadIdx.x;
    const int n0 = blockIdx.x * 64;
    const int wid = tid >> 6, lane = tid & 63;
    const int ln15 = lane & 15, kq = lane >> 4;

    const float* Wsrc; int ldw;
    if (MODE == 1) {
        if (n0 < 1024) { Wsrc = W0 + (size_t)n0 * ldw0; ldw = ldw0; }
        else           { Wsrc = W1 + (size_t)(n0 - 1024) * 1024; ldw = 1024; }
    } else { Wsrc = W0 + (size_t)n0 * ldw0; ldw = ldw0; }

    int xdst[8]; const short* xsrc[8];
    #pragma unroll
    for (int c = 0; c < 8; ++c) {
        int o = c * 256 + tid;
        int row = o >> 3, cb = o & 7;
        xsrc[c] = Xb + (size_t)row * ldx + cb * 8;
        xdst[c] = row * 64 + ((cb * 8) ^ ((row & 7) << 3));
    }
    int wdst[2]; const float* wsrcp[2];
    #pragma unroll
    for (int g = 0; g < 2; ++g) {
        int o = g * 256 + tid;
        int row = o >> 3, gb = o & 7;
        wsrcp[g] = Wsrc + (size_t)row * ldw + gb * 8;
        wdst[g] = row * 64 + ((gb * 8) ^ ((row & 7) << 3));
    }
    int aoff[2][4], boff[2][4];
    #pragma unroll
    for (int ks = 0; ks < 2; ++ks) {
        #pragma unroll
        for (int i = 0; i < 4; ++i) {
            int ar = wid * 64 + i * 16 + ln15;
            aoff[ks][i] = ar * 64 + ((ks * 32 + kq * 8) ^ ((ar & 7) << 3));
            int br = i * 16 + ln15;
            boff[ks][i] = br * 64 + ((ks * 32 + kq * 8) ^ ((br & 7) << 3));
        }
    }

    f32x4 acc[4][4];
    #pragma unroll
    for (int i = 0; i < 4; ++i)
        #pragma unroll
        for (int j = 0; j < 4; ++j) acc[i][j] = {0.f, 0.f, 0.f, 0.f};

    bf8 xA[8], xB[8];
    float4 wA[4], wB[4];

    const int NT = K >> 6;

    #pragma unroll
    for (int c = 0; c < 8; ++c) xA[c] = *(const bf8*)(xsrc[c]);
    #pragma unroll
    for (int g = 0; g < 2; ++g) {
        wA[2*g]   = *(const float4*)(wsrcp[g]);
        wA[2*g+1] = *(const float4*)(wsrcp[g] + 4);
    }

    for (int t = 0; t < NT; t += 2) {
        __syncthreads();
        #pragma unroll
        for (int c = 0; c < 8; ++c) *(bf8*)&Xs[xdst[c]] = xA[c];
        #pragma unroll
        for (int g = 0; g < 2; ++g) *(bf8*)&Ws[wdst[g]] = pack8(wA[2*g], wA[2*g+1]);
        if (t + 1 < NT) {
            int k0 = (t + 1) << 6;
            #pragma unroll
            for (int c = 0; c < 8; ++c) xB[c] = *(const bf8*)(xsrc[c] + k0);
            #pragma unroll
            for (int g = 0; g < 2; ++g) {
                wB[2*g]   = *(const float4*)(wsrcp[g] + k0);
                wB[2*g+1] = *(const float4*)(wsrcp[g] + k0 + 4);
            }
        }
        __syncthreads();
        #pragma unroll
        for (int ks = 0; ks < 2; ++ks) {
            bf8 a[4], b[4];
            #pragma unroll
            for (int i = 0; i < 4; ++i) a[i] = *(const bf8*)&Xs[aoff[ks][i]];
            #pragma unroll
            for (int j = 0; j < 4; ++j) b[j] = *(const bf8*)&Ws[boff[ks][j]];
            #pragma unroll
            for (int i = 0; i < 4; ++i)
                #pragma unroll
                for (int j = 0; j < 4; ++j)
                    acc[i][j] = __builtin_amdgcn_mfma_f32_16x16x32_bf16(a[i], b[j], acc[i][j], 0, 0, 0);
        }
        if (t + 1 >= NT) break;
        __syncthreads();
        #pragma unroll
        for (int c = 0; c < 8; ++c) *(bf8*)&Xs[xdst[c]] = xB[c];
        #pragma unroll
        for (int g = 0; g < 2; ++g) *(bf8*)&Ws[wdst[g]] = pack8(wB[2*g], wB[2*g+1]);
        if (t + 2 < NT) {
            int k0 = (t + 2) << 6;
            #pragma unroll
            for (int c = 0; c < 8; ++c) xA[c] = *(const bf8*)(xsrc[c] + k0);
            #pragma unroll
            for (int g = 0; g < 2; ++g) {
                wA[2*g]   = *(const float4*)(wsrcp[g] + k0);
                wA[2*g+1] = *(const float4*)(wsrcp[g] + k0 + 4);
            }
        }
        __syncthreads();
        #pragma unroll
        for (int ks = 0; ks < 2; ++ks) {
            bf8 a[4], b[4];
            #pragma unroll
            for (int i = 0; i < 4; ++i) a[i] = *(const bf8*)&Xs[aoff[ks][i]];
            #pragma unroll
            for (int j = 0; j < 4; ++j) b[j] = *(const bf8*)&Ws[boff[ks][j]];
            #pragma unroll
            for (int i = 0; i < 4; ++i)
                #pragma unroll
                for (int j = 0; j < 4; ++j)
                    acc[i][j] = __builtin_amdgcn_mfma_f32_16x16x32_bf16(a[i], b[j], acc[i][j], 0, 0, 0);
        }
    }

    #pragma unroll
    for (int i = 0; i < 4; ++i) {
        #pragma unroll
        for (int j = 0; j < 4; ++j) {
            int col = n0 + j * 16 + ln15;
            #pragma unroll
            for (int r = 0; r < 4; ++r) {
                int row = wid * 64 + i * 16 + kq * 4 + r;
                float v = acc[i][j][r];
                if (MODE == 1) {
                    if (n0 < 1024) out0[(size_t)row * ldo0 + col] = v;
                    else           out1[(size_t)row * 3072 + (col - 1024)] = v + bias[col - 1024];
                } else {
                    out0[(size_t)row * ldo0 + col] = v + (bias ? bias[col] : 0.f);
                }
            }
        }
    }
}

// ---------------- logits6: FIFO-clean pipelined streaming GEMM ----------------
// out[256,32000] = Xb[256,3584](bf16) @ W[32000,3584](f32)^T + bias.
// BM=256(=M), BN=64, BK=64. 256 thr = 4 waves; wave w owns rows 64w..64w+63.
// W reg-staged -> bf16 LDS (8KB single buffer). Raw s_barrier + lgkmcnt(0) only
// (no vmcnt drain at barriers). A-loads hoisted BEFORE W(u+2) issue so the
// wait-for-A never drains the W prefetch (vmcnt FIFO). 3 rolling W reg-sets.
#define LOADW(SET, T) { int k0_ = (T) * 64;                                  \
    _Pragma("unroll") for (int c_ = 0; c_ < 2; ++c_) {                       \
        SET[2*c_]   = *(const float4*)(wsrcp[c_] + k0_);                     \
        SET[2*c_+1] = *(const float4*)(wsrcp[c_] + k0_ + 4);                 \
    } }

#define STEP(T, SCUR, SPRE, DO_PRE) {                                        \
    bf8 a_[8];                                                               \
    _Pragma("unroll") for (int ks_ = 0; ks_ < 2; ++ks_)                      \
        _Pragma("unroll") for (int i_ = 0; i_ < 4; ++i_)                     \
            a_[ks_*4+i_] = *(const bf8*)(asrc[i_] + (T) * 64 + ks_ * 32);    \
    __builtin_amdgcn_sched_barrier(0);                                       \
    asm volatile("s_waitcnt lgkmcnt(0)" ::: "memory");                       \
    __builtin_amdgcn_sched_barrier(0);                                       \
    __builtin_amdgcn_s_barrier();                                            \
    _Pragma("unroll") for (int c_ = 0; c_ < 2; ++c_)                         \
        *(bf8*)&Ws[wdst[c_]] = pack8(SCUR[2*c_], SCUR[2*c_+1]);              \
    if (DO_PRE) LOADW(SPRE, (T) + 2);                                        \
    __builtin_amdgcn_sched_barrier(0);                                       \
    asm volatile("s_waitcnt lgkmcnt(0)" ::: "memory");                       \
    __builtin_amdgcn_sched_barrier(0);                                       \
    __builtin_amdgcn_s_barrier();                                            \
    _Pragma("unroll") for (int ks_ = 0; ks_ < 2; ++ks_) {                    \
        bf8 b_[4];                                                           \
        _Pragma("unroll") for (int j_ = 0; j_ < 4; ++j_)                     \
            b_[j_] = *(const bf8*)&Ws[boff[ks_][j_]];                        \
        _Pragma("unroll") for (int i_ = 0; i_ < 4; ++i_)                     \
            _Pragma("unroll") for (int j_ = 0; j_ < 4; ++j_)                 \
                acc[i_][j_] = __builtin_amdgcn_mfma_f32_16x16x32_bf16(       \
                    a_[ks_*4+i_], b_[j_], acc[i_][j_], 0, 0, 0);             \
    } }

__global__ __launch_bounds__(256) void logits6(
    const short* __restrict__ Xb,   // [256][3584] bf16
    const float* __restrict__ W,    // [32000][3584] f32
    const float* __restrict__ bias,
    float* __restrict__ out)
{
    __shared__ short Ws[64 * 64];   // 8 KB, chunk-swizzled

    const int tid = threadIdx.x;
    const int n0 = blockIdx.x * 64;
    const int wid = tid >> 6, lane = tid & 63;
    const int ln15 = lane & 15, kq = lane >> 4;
    const int m0 = wid * 64;

    // W staging: 512 bf16-chunks of 16B per tile (64 rows x 8 chunks), 2/thread.
    // Physical chunk pc holds logical chunk pc ^ (row&7); source is 8 f32 (32B).
    const float* wsrcp[2]; int wdst[2];
    #pragma unroll
    for (int c = 0; c < 2; ++c) {
        int o = c * 256 + tid;
        int row = o >> 3, pc = o & 7;
        int lc = pc ^ (row & 7);
        wsrcp[c] = W + (size_t)(n0 + row) * 3584 + lc * 8;
        wdst[c] = row * 64 + pc * 8;
    }
    // B-fragment read offsets (shorts), swizzle-matched
    int boff[2][4];
    #pragma unroll
    for (int ks = 0; ks < 2; ++ks) {
        #pragma unroll
        for (int j = 0; j < 4; ++j) {
            int br = j * 16 + ln15;
            int u = (ks * 4 + kq) ^ (br & 7);
            boff[ks][j] = br * 64 + u * 8;
        }
    }
    // A sources (L2-resident bf16)
    const short* asrc[4];
    #pragma unroll
    for (int i = 0; i < 4; ++i)
        asrc[i] = Xb + (size_t)(m0 + i * 16 + ln15) * 3584 + kq * 8;

    f32x4 acc[4][4];
    #pragma unroll
    for (int i = 0; i < 4; ++i)
        #pragma unroll
        for (int j = 0; j < 4; ++j) acc[i][j] = {0.f, 0.f, 0.f, 0.f};

    float4 w0[4], w1[4], w2[4];
    // NT = 3584/64 = 56 = 3*18 + 2
    LOADW(w0, 0);
    LOADW(w1, 1);

    for (int k = 0; k < 18; ++k) {
        int u = k * 3;
        STEP(u,     w0, w2, true);
        STEP(u + 1, w1, w0, true);
        STEP(u + 2, w2, w1, true);
    }
    STEP(54, w0, w2, false);
    STEP(55, w1, w2, false);

    // epilogue: col=lane&15 (n), row=(lane>>4)*4+r (m)
    #pragma unroll
    for (int j = 0; j < 4; ++j) {
        int col = n0 + j * 16 + ln15;
        float bv = bias[col];
        #pragma unroll
        for (int i = 0; i < 4; ++i) {
            #pragma unroll
            for (int r = 0; r < 4; ++r) {
                int row = m0 + i * 16 + kq * 4 + r;
                out[(size_t)row * 32000 + col] = acc[i][j][r] + bv;
            }
        }
    }
}
#undef LOADW
#undef STEP

// ---------------- energy: E2 = enc(f32->bf16) * Wattn2_bf^T, fused tanh/v epilogue ----------------
__global__ __launch_bounds__(512, 2) void energy2(
    const float* __restrict__ enc,
    const short* __restrict__ Wb,       // [1024][2048] bf16
    const float* __restrict__ E1,       // [256][1024]
    const float* __restrict__ b_attn,
    const float* __restrict__ v_attn,
    float* __restrict__ partials)       // [16384][16]
{
    __shared__ short Xs[128 * 64];
    __shared__ short Ws[256 * 64];

    const int tid = threadIdx.x;
    const int p = blockIdx.x;                    // 0..511
    const int logical = (p & 7) * 64 + (p >> 3); // bijective XCD chunk
    const int nb = logical & 3, n0 = nb * 256;
    const int m0 = (logical >> 2) * 128;
    const int wid = tid >> 6, lane = tid & 63;
    const int wrow = wid >> 2, wcol = wid & 3;
    const int ln15 = lane & 15, kq = lane >> 4;

    int xdst[2]; const float* xsrc[2];
    #pragma unroll
    for (int g = 0; g < 2; ++g) {
        int o = g * 512 + tid;
        int row = o >> 3, gb = o & 7;
        int m = m0 + row, b = m >> 6, l = m & 63;
        xsrc[g] = enc + ((size_t)l * B_ + b) * 2048 + gb * 8;
        xdst[g] = row * 64 + ((gb * 8) ^ ((row & 7) << 3));
    }
    int wdst[4]; const short* wsrcp[4];
    #pragma unroll
    for (int c = 0; c < 4; ++c) {
        int o = c * 512 + tid;
        int row = o >> 3, cb = o & 7;
        wsrcp[c] = Wb + (size_t)(n0 + row) * 2048 + cb * 8;
        wdst[c] = row * 64 + ((cb * 8) ^ ((row & 7) << 3));
    }
    int aoff[2][4], boff[2][4];
    #pragma unroll
    for (int ks = 0; ks < 2; ++ks) {
        #pragma unroll
        for (int i = 0; i < 4; ++i) {
            int ar = wrow * 64 + i * 16 + ln15;
            aoff[ks][i] = ar * 64 + ((ks * 32 + kq * 8) ^ ((ar & 7) << 3));
            int br = wcol * 64 + i * 16 + ln15;
            boff[ks][i] = br * 64 + ((ks * 32 + kq * 8) ^ ((br & 7) << 3));
        }
    }

    f32x4 acc[4][4];
    #pragma unroll
    for (int i = 0; i < 4; ++i)
        #pragma unroll
        for (int j = 0; j < 4; ++j) acc[i][j] = {0.f, 0.f, 0.f, 0.f};

    float4 xA[4], xB[4];
    bf8 wA[4], wB[4];

    const int NT = 32;  // K = 2048

    #pragma unroll
    for (int g = 0; g < 2; ++g) {
        xA[2*g]   = *(const float4*)(xsrc[g]);
        xA[2*g+1] = *(const float4*)(xsrc[g] + 4);
    }
    #pragma unroll
    for (int c = 0; c < 4; ++c) wA[c] = *(const bf8*)(wsrcp[c]);

    for (int t = 0; t < NT; t += 2) {
        __syncthreads();
        #pragma unroll
        for (int g = 0; g < 2; ++g) *(bf8*)&Xs[xdst[g]] = pack8(xA[2*g], xA[2*g+1]);
        #pragma unroll
        for (int c = 0; c < 4; ++c) *(bf8*)&Ws[wdst[c]] = wA[c];
        {
            int k0 = (t + 1) << 6;
            #pragma unroll
            for (int g = 0; g < 2; ++g) {
                xB[2*g]   = *(const float4*)(xsrc[g] + k0);
                xB[2*g+1] = *(const float4*)(xsrc[g] + k0 + 4);
            }
            #pragma unroll
            for (int c = 0; c < 4; ++c) wB[c] = *(const bf8*)(wsrcp[c] + k0);
        }
        __syncthreads();
        #pragma unroll
        for (int ks = 0; ks < 2; ++ks) {
            bf8 a[4], b[4];
            #pragma unroll
            for (int i = 0; i < 4; ++i) a[i] = *(const bf8*)&Xs[aoff[ks][i]];
            #pragma unroll
            for (int j = 0; j < 4; ++j) b[j] = *(const bf8*)&Ws[boff[ks][j]];
            #pragma unroll
            for (int i = 0; i < 4; ++i)
                #pragma unroll
                for (int j = 0; j < 4; ++j)
                    acc[i][j] = __builtin_amdgcn_mfma_f32_16x16x32_bf16(a[i], b[j], acc[i][j], 0, 0, 0);
        }
        __syncthreads();
        #pragma unroll
        for (int g = 0; g < 2; ++g) *(bf8*)&Xs[xdst[g]] = pack8(xB[2*g], xB[2*g+1]);
        #pragma unroll
        for (int c = 0; c < 4; ++c) *(bf8*)&Ws[wdst[c]] = wB[c];
        if (t + 2 < NT) {
            int k0 = (t + 2) << 6;
            #pragma unroll
            for (int g = 0; g < 2; ++g) {
                xA[2*g]   = *(const float4*)(xsrc[g] + k0);
                xA[2*g+1] = *(const float4*)(xsrc[g] + k0 + 4);
            }
            #pragma unroll
            for (int c = 0; c < 4; ++c) wA[c] = *(const bf8*)(wsrcp[c] + k0);
        }
        __syncthreads();
        #pragma unroll
        for (int ks = 0; ks < 2; ++ks) {
            bf8 a[4], b[4];
            #pragma unroll
            for (int i = 0; i < 4; ++i) a[i] = *(const bf8*)&Xs[aoff[ks][i]];
            #pragma unroll
            for (int j = 0; j < 4; ++j) b[j] = *(const bf8*)&Ws[boff[ks][j]];
            #pragma unroll
            for (int i = 0; i < 4; ++i)
                #pragma unroll
                for (int j = 0; j < 4; ++j)
                    acc[i][j] = __builtin_amdgcn_mfma_f32_16x16x32_bf16(a[i], b[j], acc[i][j], 0, 0, 0);
        }
    }

    float rs[4][4];
    #pragma unroll
    for (int i = 0; i < 4; ++i)
        #pragma unroll
        for (int r = 0; r < 4; ++r) rs[i][r] = 0.f;

    #pragma unroll
    for (int i = 0; i < 4; ++i) {
        #pragma unroll
        for (int j = 0; j < 4; ++j) {
            int col = n0 + wcol * 64 + j * 16 + ln15;
            float bv = b_attn[col], vv = v_attn[col];
            #pragma unroll
            for (int r = 0; r < 4; ++r) {
                int m = m0 + wrow * 64 + i * 16 + kq * 4 + r;
                float e = tanhf(acc[i][j][r] + E1[(size_t)(m >> 6) * 1024 + col] + bv);
                rs[i][r] += e * vv;
            }
        }
    }
    #pragma unroll
    for (int i = 0; i < 4; ++i)
        #pragma unroll
        for (int r = 0; r < 4; ++r) {
            float s = rs[i][r];
            #pragma unroll
            for (int off = 1; off < 16; off <<= 1) s += __shfl_xor(s, off);
            rs[i][r] = s;
        }
    if (ln15 == 0) {
        #pragma unroll
        for (int i = 0; i < 4; ++i)
            #pragma unroll
            for (int r = 0; r < 4; ++r) {
                int m = m0 + wrow * 64 + i * 16 + kq * 4 + r;
                partials[(size_t)m * 16 + nb * 4 + wcol] = rs[i][r];
            }
    }
}

// masked softmax over L=64
__global__ __launch_bounds__(64) void softmax_k(const float* __restrict__ partials,
                                                const int* __restrict__ mask,
                                                float* __restrict__ attnw)
{
    int b = blockIdx.x;
    int l = threadIdx.x;
    float s = 0.f;
    #pragma unroll
    for (int nb = 0; nb < 16; ++nb) s += partials[(size_t)(b * 64 + l) * 16 + nb];
    if (mask[b * 64 + l] != 0) s = -1e10f;
    float m = s;
    #pragma unroll
    for (int off = 32; off; off >>= 1) m = fmaxf(m, __shfl_xor(m, off));
    float e = expf(s - m);
    float sum = e;
    #pragma unroll
    for (int off = 32; off; off >>= 1) sum += __shfl_xor(sum, off);
    attnw[b * 64 + l] = e / sum;
}

// weighted -> bf16 into xgi_bf[:,512:2560] and xlo_bf[:,1024:3072]
__global__ __launch_bounds__(512) void weighted2(const float* __restrict__ attnw,
                                                 const float* __restrict__ enc,
                                                 short* __restrict__ xgi,
                                                 short* __restrict__ xlo)
{
    int b = blockIdx.x;
    int t = threadIdx.x;           // 512 threads x 4 floats = 2048
    float4 acc = {0.f, 0.f, 0.f, 0.f};
    const float* base = enc + (size_t)b * 2048 + t * 4;
    for (int l = 0; l < 64; ++l) {
        float w = attnw[b * 64 + l];
        float4 f = *(const float4*)(base + (size_t)l * B_ * 2048);
        acc.x += w * f.x; acc.y += w * f.y; acc.z += w * f.z; acc.w += w * f.w;
    }
    s4 s; s[0]=f2b(acc.x); s[1]=f2b(acc.y); s[2]=f2b(acc.z); s[3]=f2b(acc.w);
    *(s4*)(xgi + (size_t)b * 2560 + 512 + t * 4) = s;
    *(s4*)(xlo + (size_t)b * 3584 + 1024 + t * 4) = s;
}

// GRU gates; writes hnew (f32 output) and xlo_bf[:,0:1024]
__global__ __launch_bounds__(256) void gru2(const float* __restrict__ gi,
                                            const float* __restrict__ gh,
                                            const float* __restrict__ h,
                                            float* __restrict__ hnew,
                                            short* __restrict__ xlo)
{
    int idx = blockIdx.x * 256 + threadIdx.x;
    int b = idx >> 10, j = idx & 1023;
    const float* gib = gi + (size_t)b * 3072;
    const float* ghb = gh + (size_t)b * 3072;
    float r = 1.f / (1.f + expf(-(gib[j] + ghb[j])));
    float z = 1.f / (1.f + expf(-(gib[1024 + j] + ghb[1024 + j])));
    float n = tanhf(gib[2048 + j] + r * ghb[2048 + j]);
    float hv = (1.f - z) * n + z * h[idx];
    hnew[idx] = hv;
    xlo[(size_t)b * 3584 + j] = f2b(hv);
}

extern "C" void kernel_launch(void* const* d_in, const int* in_sizes, int n_in,
                              void* d_out, int out_size, void* d_ws, size_t ws_size,
                              hipStream_t stream) {
    const float* input_emb = (const float*)d_in[0];
    const float* hidden    = (const float*)d_in[1];
    const float* enc       = (const float*)d_in[2];
    const int*   mask      = (const int*)d_in[3];
    const float* W_attn = (const float*)d_in[4];
    const float* b_attn = (const float*)d_in[5];
    const float* v_attn = (const float*)d_in[6];
    const float* W_ih   = (const float*)d_in[7];
    const float* W_hh   = (const float*)d_in[8];
    const float* b_ih   = (const float*)d_in[9];
    const float* b_hh   = (const float*)d_in[10];
    const float* W_out  = (const float*)d_in[11];
    const float* b_out  = (const float*)d_in[12];

    float* logits = (float*)d_out;
    float* hnew   = logits + (size_t)B_ * V_;
    float* attnw  = hnew + (size_t)B_ * H_;

    float* ws       = (float*)d_ws;
    float* partials = ws;                                  // 262144 f
    float* E1       = partials + 262144;                   // 262144 f
    float* gi       = E1 + 262144;                         // 786432 f
    float* gh       = gi + 786432;                         // 786432 f
    short* h_bf     = (short*)(gh + 786432);               // 262144 sh
    short* xgi_bf   = h_bf + 262144;                       // 655360 sh
    short* xlo_bf   = xgi_bf + 655360;                     // 917504 sh
    short* Wattn2   = xlo_bf + 917504;                     // 2097152 sh

    conv_static<<<384, 256, 0, stream>>>(hidden, input_emb, h_bf, xgi_bf, xlo_bf);
    conv_wattn2<<<2048, 256, 0, stream>>>(W_attn, Wattn2);

    // E1 (n<1024, no bias) + gh (n>=1024, +b_hh), X = h_bf
    gemm3<1><<<64, 256, 0, stream>>>(h_bf, 1024, 1024,
                                     W_attn, 3072, W_hh, b_hh, E1, 1024, gh);
    // energy (512 blocks, XCD-swizzled internally)
    energy2<<<512, 512, 0, stream>>>(enc, Wattn2, E1, b_attn, v_attn, partials);
    softmax_k<<<B_, 64, 0, stream>>>(partials, mask, attnw);
    weighted2<<<B_, 512, 0, stream>>>(attnw, enc, xgi_bf, xlo_bf);
    // gi = xgi_bf * W_ih^T + b_ih
    gemm3<0><<<48, 256, 0, stream>>>(xgi_bf, 2560, 2560,
                                     W_ih, 2560, nullptr, b_ih, gi, 3072, nullptr);
    gru2<<<1024, 256, 0, stream>>>(gi, gh, hidden, hnew, xlo_bf);
    // logits: FIFO-clean pipelined streaming GEMM
    logits6<<<500, 256, 0, stream>>>(xlo_bf, W_out, b_out, logits);
}

// Round 12
// 393.699 us; speedup vs baseline: 1.0956x; 1.0034x over previous
//
#include <hip/hip_runtime.h>
#include <cstddef>

static constexpr int B_  = 256;
static constexpr int L_  = 64;
static constexpr int H_  = 1024;
static constexpr int IN_ = 512;
static constexpr int V_  = 32000;

typedef __attribute__((ext_vector_type(8))) short bf8;
typedef __attribute__((ext_vector_type(4))) short s4;
typedef __attribute__((ext_vector_type(4))) float f32x4;

__device__ __forceinline__ short f2b(float x) {
    unsigned u = __float_as_uint(x);
    u += 0x7fffu + ((u >> 16) & 1u);
    return (short)(u >> 16);
}
__device__ __forceinline__ bf8 pack8(const float4& a, const float4& b) {
    bf8 r;
    r[0]=f2b(a.x); r[1]=f2b(a.y); r[2]=f2b(a.z); r[3]=f2b(a.w);
    r[4]=f2b(b.x); r[5]=f2b(b.y); r[6]=f2b(b.z); r[7]=f2b(b.w);
    return r;
}

// ---------------- conversion kernels ----------------
__global__ __launch_bounds__(256) void conv_static(
    const float* __restrict__ h, const float* __restrict__ emb,
    short* __restrict__ h_bf, short* __restrict__ xgi, short* __restrict__ xlo)
{
    int u = blockIdx.x * 256 + threadIdx.x;          // float4 units
    if (u < 65536) {                                  // h: 256*1024/4
        float4 f = *(const float4*)(h + (size_t)u * 4);
        s4 s; s[0]=f2b(f.x); s[1]=f2b(f.y); s[2]=f2b(f.z); s[3]=f2b(f.w);
        *(s4*)(h_bf + (size_t)u * 4) = s;
    } else {                                          // emb: 256*512/4 = 32768
        int e = u - 65536;
        int m = e >> 7, c4 = (e & 127) * 4;
        float4 f = *(const float4*)(emb + (size_t)m * 512 + c4);
        s4 s; s[0]=f2b(f.x); s[1]=f2b(f.y); s[2]=f2b(f.z); s[3]=f2b(f.w);
        *(s4*)(xgi + (size_t)m * 2560 + c4) = s;
        *(s4*)(xlo + (size_t)m * 3584 + 3072 + c4) = s;
    }
}

__global__ __launch_bounds__(256) void conv_wattn2(
    const float* __restrict__ W_attn, short* __restrict__ Wb)
{
    int o = blockIdx.x * 256 + threadIdx.x;           // float4 units, 524288
    int r = o >> 9, c4 = (o & 511) * 4;
    float4 f = *(const float4*)(W_attn + (size_t)r * 3072 + 1024 + c4);
    s4 s; s[0]=f2b(f.x); s[1]=f2b(f.y); s[2]=f2b(f.z); s[3]=f2b(f.w);
    *(s4*)(Wb + (size_t)r * 2048 + c4) = s;
}

// ---------------- GEMM (reg-staged LDS): small GEMMs (E1+gh, gi) ----------------
template<int MODE>
__global__ __launch_bounds__(256) void gemm3(
    const short* __restrict__ Xb, int ldx, int K,
    const float* __restrict__ W0, int ldw0,
    const float* __restrict__ W1,
    const float* __restrict__ bias,
    float* __restrict__ out0, int ldo0,
    float* __restrict__ out1)
{
    __shared__ short Xs[256 * 64];
    __shared__ short Ws[64 * 64];

    const int tid = threadIdx.x;
    const int n0 = blockIdx.x * 64;
    const int wid = tid >> 6, lane = tid & 63;
    const int ln15 = lane & 15, kq = lane >> 4;

    const float* Wsrc; int ldw;
    if (MODE == 1) {
        if (n0 < 1024) { Wsrc = W0 + (size_t)n0 * ldw0; ldw = ldw0; }
        else           { Wsrc = W1 + (size_t)(n0 - 1024) * 1024; ldw = 1024; }
    } else { Wsrc = W0 + (size_t)n0 * ldw0; ldw = ldw0; }

    int xdst[8]; const short* xsrc[8];
    #pragma unroll
    for (int c = 0; c < 8; ++c) {
        int o = c * 256 + tid;
        int row = o >> 3, cb = o & 7;
        xsrc[c] = Xb + (size_t)row * ldx + cb * 8;
        xdst[c] = row * 64 + ((cb * 8) ^ ((row & 7) << 3));
    }
    int wdst[2]; const float* wsrcp[2];
    #pragma unroll
    for (int g = 0; g < 2; ++g) {
        int o = g * 256 + tid;
        int row = o >> 3, gb = o & 7;
        wsrcp[g] = Wsrc + (size_t)row * ldw + gb * 8;
        wdst[g] = row * 64 + ((gb * 8) ^ ((row & 7) << 3));
    }
    int aoff[2][4], boff[2][4];
    #pragma unroll
    for (int ks = 0; ks < 2; ++ks) {
        #pragma unroll
        for (int i = 0; i < 4; ++i) {
            int ar = wid * 64 + i * 16 + ln15;
            aoff[ks][i] = ar * 64 + ((ks * 32 + kq * 8) ^ ((ar & 7) << 3));
            int br = i * 16 + ln15;
            boff[ks][i] = br * 64 + ((ks * 32 + kq * 8) ^ ((br & 7) << 3));
        }
    }

    f32x4 acc[4][4];
    #pragma unroll
    for (int i = 0; i < 4; ++i)
        #pragma unroll
        for (int j = 0; j < 4; ++j) acc[i][j] = {0.f, 0.f, 0.f, 0.f};

    bf8 xA[8], xB[8];
    float4 wA[4], wB[4];

    const int NT = K >> 6;

    #pragma unroll
    for (int c = 0; c < 8; ++c) xA[c] = *(const bf8*)(xsrc[c]);
    #pragma unroll
    for (int g = 0; g < 2; ++g) {
        wA[2*g]   = *(const float4*)(wsrcp[g]);
        wA[2*g+1] = *(const float4*)(wsrcp[g] + 4);
    }

    for (int t = 0; t < NT; t += 2) {
        __syncthreads();
        #pragma unroll
        for (int c = 0; c < 8; ++c) *(bf8*)&Xs[xdst[c]] = xA[c];
        #pragma unroll
        for (int g = 0; g < 2; ++g) *(bf8*)&Ws[wdst[g]] = pack8(wA[2*g], wA[2*g+1]);
        if (t + 1 < NT) {
            int k0 = (t + 1) << 6;
            #pragma unroll
            for (int c = 0; c < 8; ++c) xB[c] = *(const bf8*)(xsrc[c] + k0);
            #pragma unroll
            for (int g = 0; g < 2; ++g) {
                wB[2*g]   = *(const float4*)(wsrcp[g] + k0);
                wB[2*g+1] = *(const float4*)(wsrcp[g] + k0 + 4);
            }
        }
        __syncthreads();
        #pragma unroll
        for (int ks = 0; ks < 2; ++ks) {
            bf8 a[4], b[4];
            #pragma unroll
            for (int i = 0; i < 4; ++i) a[i] = *(const bf8*)&Xs[aoff[ks][i]];
            #pragma unroll
            for (int j = 0; j < 4; ++j) b[j] = *(const bf8*)&Ws[boff[ks][j]];
            #pragma unroll
            for (int i = 0; i < 4; ++i)
                #pragma unroll
                for (int j = 0; j < 4; ++j)
                    acc[i][j] = __builtin_amdgcn_mfma_f32_16x16x32_bf16(a[i], b[j], acc[i][j], 0, 0, 0);
        }
        if (t + 1 >= NT) break;
        __syncthreads();
        #pragma unroll
        for (int c = 0; c < 8; ++c) *(bf8*)&Xs[xdst[c]] = xB[c];
        #pragma unroll
        for (int g = 0; g < 2; ++g) *(bf8*)&Ws[wdst[g]] = pack8(wB[2*g], wB[2*g+1]);
        if (t + 2 < NT) {
            int k0 = (t + 2) << 6;
            #pragma unroll
            for (int c = 0; c < 8; ++c) xA[c] = *(const bf8*)(xsrc[c] + k0);
            #pragma unroll
            for (int g = 0; g < 2; ++g) {
                wA[2*g]   = *(const float4*)(wsrcp[g] + k0);
                wA[2*g+1] = *(const float4*)(wsrcp[g] + k0 + 4);
            }
        }
        __syncthreads();
        #pragma unroll
        for (int ks = 0; ks < 2; ++ks) {
            bf8 a[4], b[4];
            #pragma unroll
            for (int i = 0; i < 4; ++i) a[i] = *(const bf8*)&Xs[aoff[ks][i]];
            #pragma unroll
            for (int j = 0; j < 4; ++j) b[j] = *(const bf8*)&Ws[boff[ks][j]];
            #pragma unroll
            for (int i = 0; i < 4; ++i)
                #pragma unroll
                for (int j = 0; j < 4; ++j)
                    acc[i][j] = __builtin_amdgcn_mfma_f32_16x16x32_bf16(a[i], b[j], acc[i][j], 0, 0, 0);
        }
    }

    #pragma unroll
    for (int i = 0; i < 4; ++i) {
        #pragma unroll
        for (int j = 0; j < 4; ++j) {
            int col = n0 + j * 16 + ln15;
            #pragma unroll
            for (int r = 0; r < 4; ++r) {
                int row = wid * 64 + i * 16 + kq * 4 + r;
                float v = acc[i][j][r];
                if (MODE == 1) {
                    if (n0 < 1024) out0[(size_t)row * ldo0 + col] = v;
                    else           out1[(size_t)row * 3072 + (col - 1024)] = v + bias[col - 1024];
                } else {
                    out0[(size_t)row * ldo0 + col] = v + (bias ? bias[col] : 0.f);
                }
            }
        }
    }
}

// ---------------- logits7: triple-buffered, ONE barrier per K-step ----------------
// out[256,32000] = Xb[256,3584](bf16) @ W[32000,3584](f32)^T + bias.
// BM=256(=M), BN=64, BK=64. 256 thr = 4 waves; wave w owns rows 64w..64w+63.
// 3 LDS bufs (24KB): step t writes tile t+1 -> buf[(t+1)%3], reads tile t from
// buf[t%3] -- WAR hazard gone, so only one s_barrier per step. W prefetch depth
// 3 (issue t+3 during step t). A-loads hoisted first (FIFO-clean vmcnt).
#define LOADW(SET, T) { int k0_ = (T) * 64;                                  \
    _Pragma("unroll") for (int c_ = 0; c_ < 2; ++c_) {                       \
        SET[2*c_]   = *(const float4*)(wsrcp[c_] + k0_);                     \
        SET[2*c_+1] = *(const float4*)(wsrcp[c_] + k0_ + 4);                 \
    } }

#define STEPL(T, SW, SL, BW, BR, DO_PRE, DO_WRITE) {                         \
    bf8 a_[8];                                                               \
    _Pragma("unroll") for (int ks_ = 0; ks_ < 2; ++ks_)                      \
        _Pragma("unroll") for (int i_ = 0; i_ < 4; ++i_)                     \
            a_[ks_*4+i_] = *(const bf8*)(asrc[i_] + (T) * 64 + ks_ * 32);    \
    __builtin_amdgcn_sched_barrier(0);                                       \
    if (DO_WRITE) {                                                          \
        _Pragma("unroll") for (int c_ = 0; c_ < 2; ++c_)                     \
            *(bf8*)&Ws[BW][wdst[c_]] = pack8(SW[2*c_], SW[2*c_+1]);          \
    }                                                                        \
    if (DO_PRE) LOADW(SL, (T) + 3);                                          \
    __builtin_amdgcn_sched_barrier(0);                                       \
    asm volatile("s_waitcnt lgkmcnt(0)" ::: "memory");                       \
    __builtin_amdgcn_sched_barrier(0);                                       \
    __builtin_amdgcn_s_barrier();                                            \
    _Pragma("unroll") for (int ks_ = 0; ks_ < 2; ++ks_) {                    \
        bf8 b_[4];                                                           \
        _Pragma("unroll") for (int j_ = 0; j_ < 4; ++j_)                     \
            b_[j_] = *(const bf8*)&Ws[BR][boff[ks_][j_]];                    \
        _Pragma("unroll") for (int i_ = 0; i_ < 4; ++i_)                     \
            _Pragma("unroll") for (int j_ = 0; j_ < 4; ++j_)                 \
                acc[i_][j_] = __builtin_amdgcn_mfma_f32_16x16x32_bf16(       \
                    a_[ks_*4+i_], b_[j_], acc[i_][j_], 0, 0, 0);             \
    } }

__global__ __launch_bounds__(256) void logits7(
    const short* __restrict__ Xb,   // [256][3584] bf16
    const float* __restrict__ W,    // [32000][3584] f32
    const float* __restrict__ bias,
    float* __restrict__ out)
{
    __shared__ short Ws[3][64 * 64];   // 3 x 8 KB, chunk-swizzled

    const int tid = threadIdx.x;
    const int n0 = blockIdx.x * 64;
    const int wid = tid >> 6, lane = tid & 63;
    const int ln15 = lane & 15, kq = lane >> 4;
    const int m0 = wid * 64;

    // W staging: 512 bf16-chunks of 16B per tile (64 rows x 8 chunks), 2/thread.
    // Physical chunk pc holds logical chunk pc ^ (row&7); source is 8 f32 (32B).
    const float* wsrcp[2]; int wdst[2];
    #pragma unroll
    for (int c = 0; c < 2; ++c) {
        int o = c * 256 + tid;
        int row = o >> 3, pc = o & 7;
        int lc = pc ^ (row & 7);
        wsrcp[c] = W + (size_t)(n0 + row) * 3584 + lc * 8;
        wdst[c] = row * 64 + pc * 8;
    }
    // B-fragment read offsets (shorts), swizzle-matched
    int boff[2][4];
    #pragma unroll
    for (int ks = 0; ks < 2; ++ks) {
        #pragma unroll
        for (int j = 0; j < 4; ++j) {
            int br = j * 16 + ln15;
            int u = (ks * 4 + kq) ^ (br & 7);
            boff[ks][j] = br * 64 + u * 8;
        }
    }
    // A sources (L2-resident bf16)
    const short* asrc[4];
    #pragma unroll
    for (int i = 0; i < 4; ++i)
        asrc[i] = Xb + (size_t)(m0 + i * 16 + ln15) * 3584 + kq * 8;

    f32x4 acc[4][4];
    #pragma unroll
    for (int i = 0; i < 4; ++i)
        #pragma unroll
        for (int j = 0; j < 4; ++j) acc[i][j] = {0.f, 0.f, 0.f, 0.f};

    float4 w0[4], w1[4], w2[4];
    // NT = 3584/64 = 56.  Prologue: tiles 0,1 in regs; tile 0 -> buf0; tile 2 issued.
    LOADW(w0, 0);
    LOADW(w1, 1);
    #pragma unroll
    for (int c = 0; c < 2; ++c) *(bf8*)&Ws[0][wdst[c]] = pack8(w0[2*c], w0[2*c+1]);
    LOADW(w2, 2);
    asm volatile("s_waitcnt lgkmcnt(0)" ::: "memory");
    __builtin_amdgcn_s_barrier();

    // steps 0..50 (17 x 3), prefetch t+3 each
    for (int k = 0; k < 17; ++k) {
        int u = k * 3;
        STEPL(u,     w1, w0, 1, 0, true, true);
        STEPL(u + 1, w2, w1, 2, 1, true, true);
        STEPL(u + 2, w0, w2, 0, 2, true, true);
    }
    // tail: t=51..55
    STEPL(51, w1, w0, 1, 0, true,  true);   // pre tile 54 -> w0
    STEPL(52, w2, w1, 2, 1, true,  true);   // pre tile 55 -> w1
    STEPL(53, w0, w0, 0, 2, false, true);   // write tile 54
    STEPL(54, w1, w0, 1, 0, false, true);   // write tile 55
    STEPL(55, w2, w0, 2, 1, false, false);  // read-only

    // epilogue: col=lane&15 (n), row=(lane>>4)*4+r (m)
    #pragma unroll
    for (int j = 0; j < 4; ++j) {
        int col = n0 + j * 16 + ln15;
        float bv = bias[col];
        #pragma unroll
        for (int i = 0; i < 4; ++i) {
            #pragma unroll
            for (int r = 0; r < 4; ++r) {
                int row = m0 + i * 16 + kq * 4 + r;
                out[(size_t)row * 32000 + col] = acc[i][j][r] + bv;
            }
        }
    }
}
#undef LOADW
#undef STEPL

// ---------------- energy: E2 = enc(f32->bf16) * Wattn2_bf^T, fused tanh/v epilogue ----------------
__global__ __launch_bounds__(512, 2) void energy2(
    const float* __restrict__ enc,
    const short* __restrict__ Wb,       // [1024][2048] bf16
    const float* __restrict__ E1,       // [256][1024]
    const float* __restrict__ b_attn,
    const float* __restrict__ v_attn,
    float* __restrict__ partials)       // [16384][16]
{
    __shared__ short Xs[128 * 64];
    __shared__ short Ws[256 * 64];

    const int tid = threadIdx.x;
    const int p = blockIdx.x;                    // 0..511
    const int logical = (p & 7) * 64 + (p >> 3); // bijective XCD chunk
    const int nb = logical & 3, n0 = nb * 256;
    const int m0 = (logical >> 2) * 128;
    const int wid = tid >> 6, lane = tid & 63;
    const int wrow = wid >> 2, wcol = wid & 3;
    const int ln15 = lane & 15, kq = lane >> 4;

    int xdst[2]; const float* xsrc[2];
    #pragma unroll
    for (int g = 0; g < 2; ++g) {
        int o = g * 512 + tid;
        int row = o >> 3, gb = o & 7;
        int m = m0 + row, b = m >> 6, l = m & 63;
        xsrc[g] = enc + ((size_t)l * B_ + b) * 2048 + gb * 8;
        xdst[g] = row * 64 + ((gb * 8) ^ ((row & 7) << 3));
    }
    int wdst[4]; const short* wsrcp[4];
    #pragma unroll
    for (int c = 0; c < 4; ++c) {
        int o = c * 512 + tid;
        int row = o >> 3, cb = o & 7;
        wsrcp[c] = Wb + (size_t)(n0 + row) * 2048 + cb * 8;
        wdst[c] = row * 64 + ((cb * 8) ^ ((row & 7) << 3));
    }
    int aoff[2][4], boff[2][4];
    #pragma unroll
    for (int ks = 0; ks < 2; ++ks) {
        #pragma unroll
        for (int i = 0; i < 4; ++i) {
            int ar = wrow * 64 + i * 16 + ln15;
            aoff[ks][i] = ar * 64 + ((ks * 32 + kq * 8) ^ ((ar & 7) << 3));
            int br = wcol * 64 + i * 16 + ln15;
            boff[ks][i] = br * 64 + ((ks * 32 + kq * 8) ^ ((br & 7) << 3));
        }
    }

    f32x4 acc[4][4];
    #pragma unroll
    for (int i = 0; i < 4; ++i)
        #pragma unroll
        for (int j = 0; j < 4; ++j) acc[i][j] = {0.f, 0.f, 0.f, 0.f};

    float4 xA[4], xB[4];
    bf8 wA[4], wB[4];

    const int NT = 32;  // K = 2048

    #pragma unroll
    for (int g = 0; g < 2; ++g) {
        xA[2*g]   = *(const float4*)(xsrc[g]);
        xA[2*g+1] = *(const float4*)(xsrc[g] + 4);
    }
    #pragma unroll
    for (int c = 0; c < 4; ++c) wA[c] = *(const bf8*)(wsrcp[c]);

    for (int t = 0; t < NT; t += 2) {
        __syncthreads();
        #pragma unroll
        for (int g = 0; g < 2; ++g) *(bf8*)&Xs[xdst[g]] = pack8(xA[2*g], xA[2*g+1]);
        #pragma unroll
        for (int c = 0; c < 4; ++c) *(bf8*)&Ws[wdst[c]] = wA[c];
        {
            int k0 = (t + 1) << 6;
            #pragma unroll
            for (int g = 0; g < 2; ++g) {
                xB[2*g]   = *(const float4*)(xsrc[g] + k0);
                xB[2*g+1] = *(const float4*)(xsrc[g] + k0 + 4);
            }
            #pragma unroll
            for (int c = 0; c < 4; ++c) wB[c] = *(const bf8*)(wsrcp[c] + k0);
        }
        __syncthreads();
        #pragma unroll
        for (int ks = 0; ks < 2; ++ks) {
            bf8 a[4], b[4];
            #pragma unroll
            for (int i = 0; i < 4; ++i) a[i] = *(const bf8*)&Xs[aoff[ks][i]];
            #pragma unroll
            for (int j = 0; j < 4; ++j) b[j] = *(const bf8*)&Ws[boff[ks][j]];
            #pragma unroll
            for (int i = 0; i < 4; ++i)
                #pragma unroll
                for (int j = 0; j < 4; ++j)
                    acc[i][j] = __builtin_amdgcn_mfma_f32_16x16x32_bf16(a[i], b[j], acc[i][j], 0, 0, 0);
        }
        __syncthreads();
        #pragma unroll
        for (int g = 0; g < 2; ++g) *(bf8*)&Xs[xdst[g]] = pack8(xB[2*g], xB[2*g+1]);
        #pragma unroll
        for (int c = 0; c < 4; ++c) *(bf8*)&Ws[wdst[c]] = wB[c];
        if (t + 2 < NT) {
            int k0 = (t + 2) << 6;
            #pragma unroll
            for (int g = 0; g < 2; ++g) {
                xA[2*g]   = *(const float4*)(xsrc[g] + k0);
                xA[2*g+1] = *(const float4*)(xsrc[g] + k0 + 4);
            }
            #pragma unroll
            for (int c = 0; c < 4; ++c) wA[c] = *(const bf8*)(wsrcp[c] + k0);
        }
        __syncthreads();
        #pragma unroll
        for (int ks = 0; ks < 2; ++ks) {
            bf8 a[4], b[4];
            #pragma unroll
            for (int i = 0; i < 4; ++i) a[i] = *(const bf8*)&Xs[aoff[ks][i]];
            #pragma unroll
            for (int j = 0; j < 4; ++j) b[j] = *(const bf8*)&Ws[boff[ks][j]];
            #pragma unroll
            for (int i = 0; i < 4; ++i)
                #pragma unroll
                for (int j = 0; j < 4; ++j)
                    acc[i][j] = __builtin_amdgcn_mfma_f32_16x16x32_bf16(a[i], b[j], acc[i][j], 0, 0, 0);
        }
    }

    float rs[4][4];
    #pragma unroll
    for (int i = 0; i < 4; ++i)
        #pragma unroll
        for (int r = 0; r < 4; ++r) rs[i][r] = 0.f;

    #pragma unroll
    for (int i = 0; i < 4; ++i) {
        #pragma unroll
        for (int j = 0; j < 4; ++j) {
            int col = n0 + wcol * 64 + j * 16 + ln15;
            float bv = b_attn[col], vv = v_attn[col];
            #pragma unroll
            for (int r = 0; r < 4; ++r) {
                int m = m0 + wrow * 64 + i * 16 + kq * 4 + r;
                float e = tanhf(acc[i][j][r] + E1[(size_t)(m >> 6) * 1024 + col] + bv);
                rs[i][r] += e * vv;
            }
        }
    }
    #pragma unroll
    for (int i = 0; i < 4; ++i)
        #pragma unroll
        for (int r = 0; r < 4; ++r) {
            float s = rs[i][r];
            #pragma unroll
            for (int off = 1; off < 16; off <<= 1) s += __shfl_xor(s, off);
            rs[i][r] = s;
        }
    if (ln15 == 0) {
        #pragma unroll
        for (int i = 0; i < 4; ++i)
            #pragma unroll
            for (int r = 0; r < 4; ++r) {
                int m = m0 + wrow * 64 + i * 16 + kq * 4 + r;
                partials[(size_t)m * 16 + nb * 4 + wcol] = rs[i][r];
            }
    }
}

// masked softmax over L=64
__global__ __launch_bounds__(64) void softmax_k(const float* __restrict__ partials,
                                                const int* __restrict__ mask,
                                                float* __restrict__ attnw)
{
    int b = blockIdx.x;
    int l = threadIdx.x;
    float s = 0.f;
    #pragma unroll
    for (int nb = 0; nb < 16; ++nb) s += partials[(size_t)(b * 64 + l) * 16 + nb];
    if (mask[b * 64 + l] != 0) s = -1e10f;
    float m = s;
    #pragma unroll
    for (int off = 32; off; off >>= 1) m = fmaxf(m, __shfl_xor(m, off));
    float e = expf(s - m);
    float sum = e;
    #pragma unroll
    for (int off = 32; off; off >>= 1) sum += __shfl_xor(sum, off);
    attnw[b * 64 + l] = e / sum;
}

// weighted -> bf16 into xgi_bf[:,512:2560] and xlo_bf[:,1024:3072]
__global__ __launch_bounds__(512) void weighted2(const float* __restrict__ attnw,
                                                 const float* __restrict__ enc,
                                                 short* __restrict__ xgi,
                                                 short* __restrict__ xlo)
{
    int b = blockIdx.x;
    int t = threadIdx.x;           // 512 threads x 4 floats = 2048
    float4 acc = {0.f, 0.f, 0.f, 0.f};
    const float* base = enc + (size_t)b * 2048 + t * 4;
    for (int l = 0; l < 64; ++l) {
        float w = attnw[b * 64 + l];
        float4 f = *(const float4*)(base + (size_t)l * B_ * 2048);
        acc.x += w * f.x; acc.y += w * f.y; acc.z += w * f.z; acc.w += w * f.w;
    }
    s4 s; s[0]=f2b(acc.x); s[1]=f2b(acc.y); s[2]=f2b(acc.z); s[3]=f2b(acc.w);
    *(s4*)(xgi + (size_t)b * 2560 + 512 + t * 4) = s;
    *(s4*)(xlo + (size_t)b * 3584 + 1024 + t * 4) = s;
}

// GRU gates; writes hnew (f32 output) and xlo_bf[:,0:1024]
__global__ __launch_bounds__(256) void gru2(const float* __restrict__ gi,
                                            const float* __restrict__ gh,
                                            const float* __restrict__ h,
                                            float* __restrict__ hnew,
                                            short* __restrict__ xlo)
{
    int idx = blockIdx.x * 256 + threadIdx.x;
    int b = idx >> 10, j = idx & 1023;
    const float* gib = gi + (size_t)b * 3072;
    const float* ghb = gh + (size_t)b * 3072;
    float r = 1.f / (1.f + expf(-(gib[j] + ghb[j])));
    float z = 1.f / (1.f + expf(-(gib[1024 + j] + ghb[1024 + j])));
    float n = tanhf(gib[2048 + j] + r * ghb[2048 + j]);
    float hv = (1.f - z) * n + z * h[idx];
    hnew[idx] = hv;
    xlo[(size_t)b * 3584 + j] = f2b(hv);
}

extern "C" void kernel_launch(void* const* d_in, const int* in_sizes, int n_in,
                              void* d_out, int out_size, void* d_ws, size_t ws_size,
                              hipStream_t stream) {
    const float* input_emb = (const float*)d_in[0];
    const float* hidden    = (const float*)d_in[1];
    const float* enc       = (const float*)d_in[2];
    const int*   mask      = (const int*)d_in[3];
    const float* W_attn = (const float*)d_in[4];
    const float* b_attn = (const float*)d_in[5];
    const float* v_attn = (const float*)d_in[6];
    const float* W_ih   = (const float*)d_in[7];
    const float* W_hh   = (const float*)d_in[8];
    const float* b_ih   = (const float*)d_in[9];
    const float* b_hh   = (const float*)d_in[10];
    const float* W_out  = (const float*)d_in[11];
    const float* b_out  = (const float*)d_in[12];

    float* logits = (float*)d_out;
    float* hnew   = logits + (size_t)B_ * V_;
    float* attnw  = hnew + (size_t)B_ * H_;

    float* ws       = (float*)d_ws;
    float* partials = ws;                                  // 262144 f
    float* E1       = partials + 262144;                   // 262144 f
    float* gi       = E1 + 262144;                         // 786432 f
    float* gh       = gi + 786432;                         // 786432 f
    short* h_bf     = (short*)(gh + 786432);               // 262144 sh
    short* xgi_bf   = h_bf + 262144;                       // 655360 sh
    short* xlo_bf   = xgi_bf + 655360;                     // 917504 sh
    short* Wattn2   = xlo_bf + 917504;                     // 2097152 sh

    conv_static<<<384, 256, 0, stream>>>(hidden, input_emb, h_bf, xgi_bf, xlo_bf);
    conv_wattn2<<<2048, 256, 0, stream>>>(W_attn, Wattn2);

    // E1 (n<1024, no bias) + gh (n>=1024, +b_hh), X = h_bf
    gemm3<1><<<64, 256, 0, stream>>>(h_bf, 1024, 1024,
                                     W_attn, 3072, W_hh, b_hh, E1, 1024, gh);
    // energy (512 blocks, XCD-swizzled internally)
    energy2<<<512, 512, 0, stream>>>(enc, Wattn2, E1, b_attn, v_attn, partials);
    softmax_k<<<B_, 64, 0, stream>>>(partials, mask, attnw);
    weighted2<<<B_, 512, 0, stream>>>(attnw, enc, xgi_bf, xlo_bf);
    // gi = xgi_bf * W_ih^T + b_ih
    gemm3<0><<<48, 256, 0, stream>>>(xgi_bf, 2560, 2560,
                                     W_ih, 2560, nullptr, b_ih, gi, 3072, nullptr);
    gru2<<<1024, 256, 0, stream>>>(gi, gh, hidden, hnew, xlo_bf);
    // logits: triple-buffered single-barrier streaming GEMM
    logits7<<<500, 256, 0, stream>>>(xlo_bf, W_out, b_out, logits);
}